// Round 9
// baseline (433.262 us; speedup 1.0000x reference)
//
#include <hip/hip_runtime.h>

namespace {

constexpr int kB = 16;
constexpr int kM = 1024;
constexpr int kT = 4096;
constexpr int kD = 512;
constexpr int kV = 32000;

typedef __attribute__((ext_vector_type(8))) short bfrag8;
typedef __attribute__((ext_vector_type(4))) float f4acc;

__device__ __forceinline__ ushort f2bf(float f) {
  unsigned u = __float_as_uint(f);
  u += 0x7fffu + ((u >> 16) & 1u);
  return (ushort)(u >> 16);
}
__device__ __forceinline__ float bf2f(ushort h) {
  return __uint_as_float(((unsigned)h) << 16);
}

__device__ __forceinline__ void gload_lds16(const void* g, void* l) {
  __builtin_amdgcn_global_load_lds(
      (const __attribute__((address_space(1))) void*)g,
      (__attribute__((address_space(3))) void*)l, 16, 0, 0);
}

// ---------------- fp32 -> bf16 conversion ----------------
__global__ __launch_bounds__(256) void cvt_bf16_k(
    const float4* __restrict__ in, ushort4* __restrict__ out, int n4)
{
  int i = blockIdx.x * 256 + threadIdx.x;
  if (i >= n4) return;
  float4 v = in[i];
  ushort4 o;
  o.x = f2bf(v.x); o.y = f2bf(v.y); o.z = f2bf(v.z); o.w = f2bf(v.w);
  out[i] = o;
}

// ---------------- small 512x512 fp32 matmul: C[e,k] = sum_a P[e,a]*Q[a,k] ----
template<int BF16OUT>
__global__ __launch_bounds__(512) void smallmm_k(
    const float* __restrict__ P, int strideP, int offsP,
    const float* __restrict__ Q,
    float* __restrict__ outf, ushort* __restrict__ outb)
{
  __shared__ float prow[4][512];
  int e0 = blockIdx.x * 4;
  int k = threadIdx.x;
#pragma unroll
  for (int i = 0; i < 4; ++i)
    prow[i][k] = P[(size_t)(e0 + i) * strideP + offsP + k];
  __syncthreads();
  float acc[4] = {0.f, 0.f, 0.f, 0.f};
  for (int a = 0; a < 512; ++a) {
    float qv = Q[a * 512 + k];
#pragma unroll
    for (int i = 0; i < 4; ++i) acc[i] = fmaf(prow[i][a], qv, acc[i]);
  }
#pragma unroll
  for (int i = 0; i < 4; ++i) {
    if constexpr (BF16OUT) outb[(e0 + i) * 512 + k] = f2bf(acc[i]);
    else outf[(e0 + i) * 512 + k] = acc[i];
  }
}

// ---------------- gather bf16 rows (1 KB each) ----------------
__global__ __launch_bounds__(256) void gather_rows16_k(
    const uint4* __restrict__ src, const int* __restrict__ ids,
    uint4* __restrict__ dst, int nrows)
{
  int i = blockIdx.x * 256 + threadIdx.x;
  if (i >= nrows * 64) return;
  int row = i >> 6;
  int c = i & 63;
  dst[i] = src[(size_t)ids[row] * 64 + c];
}

// ---------------- CSR build, O(T) atomic counting-sort (deterministic) ----------
__global__ __launch_bounds__(256) void zero_k(int* __restrict__ p, int n) {
  int i = blockIdx.x * 256 + threadIdx.x;
  if (i < n) p[i] = 0;
}

__global__ __launch_bounds__(256) void deg_count_k(
    const int* __restrict__ headp, const int* __restrict__ tailp,
    const int* __restrict__ lblp, int* __restrict__ deg)
{
  int i = blockIdx.x * 256 + threadIdx.x;
  if (i >= kB * kT) return;
  if (lblp[i] == -1) return;
  int b = i >> 12;
  atomicAdd(&deg[(b << 10) + tailp[i]], 1);
  atomicAdd(&deg[(b << 10) + headp[i]], 1);
}

__global__ __launch_bounds__(1024) void scan_k(
    const int* __restrict__ deg, int* __restrict__ rowstart,
    int* __restrict__ fillptr)
{
  __shared__ int s[kM];
  int b = blockIdx.x;
  int tid = threadIdx.x;
  int d = deg[b * kM + tid];
  s[tid] = d;
  __syncthreads();
  for (int off = 1; off < kM; off <<= 1) {
    int add = (tid >= off) ? s[tid - off] : 0;
    __syncthreads();
    s[tid] += add;
    __syncthreads();
  }
  int rs = b * (2 * kT) + s[tid] - d;
  rowstart[b * kM + tid] = rs;
  fillptr[b * kM + tid] = rs;
}

// pack: (seq = 2t + isHeadEntry) << 10 | src
__global__ __launch_bounds__(256) void fill_k(
    const int* __restrict__ headp, const int* __restrict__ tailp,
    const int* __restrict__ lblp, int* __restrict__ fillptr,
    int* __restrict__ epack)
{
  int i = blockIdx.x * 256 + threadIdx.x;
  if (i >= kB * kT) return;
  if (lblp[i] == -1) return;
  int b = i >> 12;
  int t = i & (kT - 1);
  int hd = headp[i];
  int tl = tailp[i];
  int p0 = atomicAdd(&fillptr[(b << 10) + tl], 1);
  epack[p0] = ((t * 2) << 10) | hd;
  int p1 = atomicAdd(&fillptr[(b << 10) + hd], 1);
  epack[p1] = ((t * 2 + 1) << 10) | tl;
}

__global__ __launch_bounds__(256) void sort_k(
    const int* __restrict__ rowstart, const int* __restrict__ deg,
    int* __restrict__ epack)
{
  int bm = blockIdx.x * 256 + threadIdx.x;
  if (bm >= kB * kM) return;
  int rs = rowstart[bm];
  int dg = deg[bm];
  for (int i = 1; i < dg; ++i) {
    int key = epack[rs + i];
    int j = i - 1;
    while (j >= 0 && epack[rs + j] > key) {
      epack[rs + j + 1] = epack[rs + j];
      --j;
    }
    epack[rs + j + 1] = key;
  }
}

// ---- fused hop-1 aggregate: Sxn = (sum X[src])/cnt ; nSr0n = -(sum EMB[rid])/cnt
__global__ __launch_bounds__(128) void agg_xr_k(
    const ushort4* __restrict__ Xv, const ushort4* __restrict__ EMBv,
    const int* __restrict__ relid,
    const int* __restrict__ deg, const int* __restrict__ rowstart,
    const int* __restrict__ epack,
    ushort4* __restrict__ Sxn, ushort4* __restrict__ nSr0n)
{
  int bm = blockIdx.x;
  int b = bm >> 10;
  int tid = threadIdx.x;
  int dg = deg[bm];
  int rs = rowstart[bm];
  const int* rid = relid + (b << 12);
  size_t xbase = (size_t)b * kM * 128;
  float ax = 0.f, ay = 0.f, az = 0.f, aw = 0.f;
  float rx = 0.f, ry = 0.f, rz = 0.f, rw = 0.f;
  for (int e = 0; e < dg; ++e) {
    int pk = epack[rs + e];
    int src = pk & 1023;
    int t = pk >> 11;
    ushort4 xv = Xv[xbase + (size_t)src * 128 + tid];
    ushort4 rv = EMBv[(size_t)rid[t] * 128 + tid];
    ax += bf2f(xv.x); ay += bf2f(xv.y); az += bf2f(xv.z); aw += bf2f(xv.w);
    rx += bf2f(rv.x); ry += bf2f(rv.y); rz += bf2f(rv.z); rw += bf2f(rv.w);
  }
  float s = 1.0f / (float)(dg > 0 ? dg : 1);
  ushort4 o;
  o.x = f2bf(ax * s); o.y = f2bf(ay * s); o.z = f2bf(az * s); o.w = f2bf(aw * s);
  Sxn[(size_t)bm * 128 + tid] = o;
  o.x = f2bf(-rx * s); o.y = f2bf(-ry * s);
  o.z = f2bf(-rz * s); o.w = f2bf(-rw * s);
  nSr0n[(size_t)bm * 128 + tid] = o;
}

// ---------------- Sxn[bm] = (sum_edges X[src]) / max(cnt,1) ----------
__global__ __launch_bounds__(128) void agg_x_k(
    const ushort4* __restrict__ Xv,
    const int* __restrict__ deg, const int* __restrict__ rowstart,
    const int* __restrict__ epack, ushort4* __restrict__ outv)
{
  int bm = blockIdx.x;
  int b = bm >> 10;
  int tid = threadIdx.x;
  int dg = deg[bm];
  int rs = rowstart[bm];
  size_t xbase = (size_t)b * kM * 128;
  float ax = 0.f, ay = 0.f, az = 0.f, aw = 0.f;
  for (int e = 0; e < dg; ++e) {
    int src = epack[rs + e] & 1023;
    ushort4 xv = Xv[xbase + (size_t)src * 128 + tid];
    ax += bf2f(xv.x); ay += bf2f(xv.y); az += bf2f(xv.z); aw += bf2f(xv.w);
  }
  float s = 1.0f / (float)(dg > 0 ? dg : 1);
  ushort4 o;
  o.x = f2bf(ax * s); o.y = f2bf(ay * s); o.z = f2bf(az * s); o.w = f2bf(aw * s);
  outv[(size_t)bm * 128 + tid] = o;
}

// ---------------- bf16 MFMA GEMM (128x128 tile, 2-barrier LDS loop) ----------
// MODE 0: C = relu([X|Sxn|nSr0n] @ [W1|W2|W3]^T), K=1536, in-place X. SWZ.
// MODE 4: C = X2 @ [Wt1|Wt3]^T (N=1024, bf16 out stride 1024). SWZ.
template<int MODE>
__global__ __launch_bounds__(256) void gemm_k(
    const ushort* __restrict__ A0, const ushort* __restrict__ A1,
    const ushort* __restrict__ A2,
    const ushort* __restrict__ W1, const ushort* __restrict__ W2,
    const ushort* __restrict__ W3,
    ushort* __restrict__ outbf)
{
  constexpr int NSEG = (MODE == 0) ? 3 : 1;
  constexpr int NC = (MODE == 4) ? 8 : 4;
  constexpr int OSTR = (MODE == 4) ? 1024 : 512;

  __shared__ __align__(16) char lds[32768];
  char* ldsA = lds;
  char* ldsB = lds + 16384;
  const int tid = threadIdx.x;
  const int w = tid >> 6;
  const int l = tid & 63;
  const int wr = w >> 1;
  const int wc = w & 1;
  const int bid = blockIdx.x;
  const int xcd = bid & 7;
  const int idx = bid >> 3;
  const int panel = xcd * (((int)gridDim.x >> 3) / NC) + idx / NC;
  const int col = idx % NC;
  const int rowBase = panel * 128;
  const int colBase = col * 128;

  f4acc acc[4][4];
#pragma unroll
  for (int i = 0; i < 4; ++i)
#pragma unroll
    for (int j = 0; j < 4; ++j) acc[i][j] = (f4acc)(0.f);

  int lrow[4], gc[4];
#pragma unroll
  for (int i = 0; i < 4; ++i) {
    int P = (i * 4 + w) * 64 + l;
    lrow[i] = P >> 3;
    gc[i] = (P & 7) ^ (lrow[i] & 7);
  }

  for (int seg = 0; seg < NSEG; ++seg) {
    const char* aP[4];
    const char* bP[4];
#pragma unroll
    for (int i = 0; i < 4; ++i) {
      int grow = rowBase + lrow[i];
      const ushort* ab;
      if constexpr (MODE == 0) {
        ab = (seg == 0 ? A0 : (seg == 1 ? A1 : A2)) + (size_t)grow * kD;
      } else {
        ab = A0 + (size_t)grow * kD;
      }
      aP[i] = (const char*)ab + gc[i] * 16;
      int e = colBase + lrow[i];
      const ushort* wb;
      if constexpr (MODE == 0) {
        wb = (seg == 0 ? W1 : (seg == 1 ? W2 : W3)) + (size_t)e * kD;
      } else {
        wb = W1 + (size_t)(e & 511) * 1536 + (e >> 9) * 1024;
      }
      bP[i] = (const char*)wb + gc[i] * 16;
    }
    for (int kcl = 0; kcl < 8; ++kcl) {
      __syncthreads();
#pragma unroll
      for (int i = 0; i < 4; ++i) {
        gload_lds16(aP[i] + kcl * 128, ldsA + (i * 4 + w) * 1024);
        gload_lds16(bP[i] + kcl * 128, ldsB + (i * 4 + w) * 1024);
      }
      __syncthreads();
#pragma unroll
      for (int ksub = 0; ksub < 2; ++ksub) {
        bfrag8 ef[4], wf[4];
#pragma unroll
        for (int mi = 0; mi < 4; ++mi) {
          int r = wr * 64 + mi * 16 + (l & 15);
          int g = (ksub * 4 + (l >> 4)) ^ (r & 7);
          ef[mi] = *(const bfrag8*)(ldsA + r * 128 + g * 16);
        }
#pragma unroll
        for (int ni = 0; ni < 4; ++ni) {
          int e = wc * 64 + ni * 16 + (l & 15);
          int g = (ksub * 4 + (l >> 4)) ^ (e & 7);
          wf[ni] = *(const bfrag8*)(ldsB + e * 128 + g * 16);
        }
#pragma unroll
        for (int mi = 0; mi < 4; ++mi)
#pragma unroll
          for (int ni = 0; ni < 4; ++ni)
            acc[mi][ni] = __builtin_amdgcn_mfma_f32_16x16x32_bf16(
                wf[ni], ef[mi], acc[mi][ni], 0, 0, 0);
      }
    }
  }

  // epilogue (swapped layout): row = ..+(l&15); cols 4-consecutive
#pragma unroll
  for (int mi = 0; mi < 4; ++mi) {
    int rr = rowBase + wr * 64 + mi * 16 + (l & 15);
#pragma unroll
    for (int ni = 0; ni < 4; ++ni) {
      int cc0 = colBase + wc * 64 + ni * 16 + (l >> 4) * 4;
      float v0 = acc[mi][ni][0], v1 = acc[mi][ni][1];
      float v2 = acc[mi][ni][2], v3 = acc[mi][ni][3];
      if constexpr (MODE == 0) {
        v0 = fmaxf(v0, 0.f); v1 = fmaxf(v1, 0.f);
        v2 = fmaxf(v2, 0.f); v3 = fmaxf(v3, 0.f);
      }
      ushort4 o;
      o.x = f2bf(v0); o.y = f2bf(v1); o.z = f2bf(v2); o.w = f2bf(v3);
      *(ushort4*)(outbf + (size_t)rr * OSTR + cc0) = o;
    }
  }
}

// ---------------- final GEMM: barrier-free, all-register fragments ----------
// out = EMBb[relid] @ Wfold^T + HT[head].H + HT[tail].T (fp32) + col partials.
// Fragment layout (direct global load, matches LDS path exactly):
//   lane l, frag mi: A row r = rowBase+wr*64+mi*16+(l&15), k-slice (l>>4)*8.
// No LDS staging, no __syncthreads in the K-loop: waves independent, gather
// latency hidden by TLP + register double-buffer 2 chunks deep.
__global__ __launch_bounds__(256) void gemm3_k(
    const ushort* __restrict__ EMBb, const ushort* __restrict__ Wf,
    const int* __restrict__ relid, const int* __restrict__ headp,
    const int* __restrict__ tailp, const ushort* __restrict__ HT,
    float* __restrict__ outf, float* __restrict__ part)
{
  const int tid = threadIdx.x;
  const int w = tid >> 6;
  const int l = tid & 63;
  const int wr = w >> 1;
  const int wc = w & 1;
  const int bid = blockIdx.x;
  const int rowBase = (bid >> 2) * 128;
  const int colBase = (bid & 3) * 128;
  const int lane16 = l & 15;
  const int sl = l >> 4;

  const ushort* aRow[4];
  const ushort* wCol[4];
#pragma unroll
  for (int mi = 0; mi < 4; ++mi) {
    int r = rowBase + wr * 64 + mi * 16 + lane16;
    aRow[mi] = EMBb + (size_t)relid[r] * kD + sl * 8;
  }
#pragma unroll
  for (int ni = 0; ni < 4; ++ni) {
    int e = colBase + wc * 64 + ni * 16 + lane16;
    wCol[ni] = Wf + (size_t)e * kD + sl * 8;
  }

  f4acc acc[4][4];
#pragma unroll
  for (int i = 0; i < 4; ++i)
#pragma unroll
    for (int j = 0; j < 4; ++j) acc[i][j] = (f4acc)(0.f);

  bfrag8 aA[4], wA[4], aB[4], wB[4];
#pragma unroll
  for (int mi = 0; mi < 4; ++mi) aA[mi] = *(const bfrag8*)(aRow[mi]);
#pragma unroll
  for (int ni = 0; ni < 4; ++ni) wA[ni] = *(const bfrag8*)(wCol[ni]);
#pragma unroll
  for (int mi = 0; mi < 4; ++mi) aB[mi] = *(const bfrag8*)(aRow[mi] + 32);
#pragma unroll
  for (int ni = 0; ni < 4; ++ni) wB[ni] = *(const bfrag8*)(wCol[ni] + 32);

#pragma unroll
  for (int cc = 0; cc < 8; ++cc) {
    // consume chunk 2cc (buffer A)
#pragma unroll
    for (int mi = 0; mi < 4; ++mi)
#pragma unroll
      for (int ni = 0; ni < 4; ++ni)
        acc[mi][ni] = __builtin_amdgcn_mfma_f32_16x16x32_bf16(
            wA[ni], aA[mi], acc[mi][ni], 0, 0, 0);
    if (cc < 7) {
      const int c2 = (2 * cc + 2) * 32;
#pragma unroll
      for (int mi = 0; mi < 4; ++mi) aA[mi] = *(const bfrag8*)(aRow[mi] + c2);
#pragma unroll
      for (int ni = 0; ni < 4; ++ni) wA[ni] = *(const bfrag8*)(wCol[ni] + c2);
    }
    // consume chunk 2cc+1 (buffer B)
#pragma unroll
    for (int mi = 0; mi < 4; ++mi)
#pragma unroll
      for (int ni = 0; ni < 4; ++ni)
        acc[mi][ni] = __builtin_amdgcn_mfma_f32_16x16x32_bf16(
            wB[ni], aB[mi], acc[mi][ni], 0, 0, 0);
    if (cc < 7) {
      const int c3 = (2 * cc + 3) * 32;
#pragma unroll
      for (int mi = 0; mi < 4; ++mi) aB[mi] = *(const bfrag8*)(aRow[mi] + c3);
#pragma unroll
      for (int ni = 0; ni < 4; ++ni) wB[ni] = *(const bfrag8*)(wCol[ni] + c3);
    }
  }

  // epilogue: rr = A-row (l&15 based), cc = W-col, 4 consecutive per frag
  __shared__ float colsum[2][128];
  colsum[tid >> 7][tid & 127] = 0.f;
  __syncthreads();
  float cs[4][4];
#pragma unroll
  for (int ni = 0; ni < 4; ++ni)
#pragma unroll
    for (int q = 0; q < 4; ++q) cs[ni][q] = 0.f;
#pragma unroll
  for (int mi = 0; mi < 4; ++mi) {
    int rr = rowBase + wr * 64 + mi * 16 + lane16;
    int bb = rr >> 12;
    int hid = headp[rr];
    int tl = tailp[rr];
    const ushort* Hrow = HT + ((size_t)(bb << 10) + hid) * 1024;
    const ushort* Trow = HT + ((size_t)(bb << 10) + tl) * 1024 + 512;
#pragma unroll
    for (int ni = 0; ni < 4; ++ni) {
      int cc0 = colBase + wc * 64 + ni * 16 + sl * 4;
      ushort4 hv = *(const ushort4*)(Hrow + cc0);
      ushort4 tv = *(const ushort4*)(Trow + cc0);
      float4 ov;
      ov.x = acc[mi][ni][0] + bf2f(hv.x) + bf2f(tv.x);
      ov.y = acc[mi][ni][1] + bf2f(hv.y) + bf2f(tv.y);
      ov.z = acc[mi][ni][2] + bf2f(hv.z) + bf2f(tv.z);
      ov.w = acc[mi][ni][3] + bf2f(hv.w) + bf2f(tv.w);
      cs[ni][0] += ov.x; cs[ni][1] += ov.y;
      cs[ni][2] += ov.z; cs[ni][3] += ov.w;
      *(float4*)(outf + (size_t)rr * 512 + cc0) = ov;
    }
  }
#pragma unroll
  for (int ni = 0; ni < 4; ++ni) {
#pragma unroll
    for (int q = 0; q < 4; ++q) {
      float s = cs[ni][q];
      s += __shfl_xor(s, 1);
      s += __shfl_xor(s, 2);
      s += __shfl_xor(s, 4);
      s += __shfl_xor(s, 8);
      if ((l & 15) == 0)
        colsum[wr][wc * 64 + ni * 16 + sl * 4 + q] = s;
    }
  }
  __syncthreads();
  if (tid < 128) {
    int bb = rowBase >> 12;
    int rt = (rowBase >> 7) & 31;
    part[(size_t)(bb * 32 + rt) * 512 + colBase + tid] =
        colsum[0][tid] + colsum[1][tid];
  }
}

// ---------------- encoded_cause: sum 32 row-tile partials per batch ----------
__global__ __launch_bounds__(512) void reduce_enc_k(
    const float* __restrict__ part, float* __restrict__ enc)
{
  int b = blockIdx.x;
  int c = threadIdx.x;
  float s = 0.f;
  for (int rt = 0; rt < 32; ++rt) s += part[(size_t)(b * 32 + rt) * 512 + c];
  enc[b * 512 + c] = s;
}

}  // namespace

extern "C" void kernel_launch(void* const* d_in, const int* in_sizes, int n_in,
                              void* d_out, int out_size, void* d_ws, size_t ws_size,
                              hipStream_t stream) {
  const float* emb = (const float*)d_in[0];
  const float* Ws = (const float*)d_in[1];
  const float* Wn = (const float*)d_in[2];
  const float* Wr = (const float*)d_in[3];
  const float* Wt = (const float*)d_in[4];
  const int* cid = (const int*)d_in[5];
  const int* relid = (const int*)d_in[6];
  const int* headp = (const int*)d_in[7];
  const int* tailp = (const int*)d_in[8];
  const int* lblp = (const int*)d_in[9];
  float* out = (float*)d_out;

  // ---- ws layout (~72 MB) ----
  char* wsp = (char*)d_ws;
  ushort* EMBb  = (ushort*)(wsp);                        // 31.25 MB @0
  ushort* HT    = (ushort*)(wsp + (32ull << 20));        // 32 MB @32
  ushort* Wsb   = (ushort*)(wsp + (64ull << 20));        // 1 MB (2 hops)
  ushort* Wnb   = (ushort*)(wsp + (65ull << 20));        // 1 MB (2 hops)
  ushort* Wtb   = (ushort*)(wsp + (66ull << 20));        // 1.5 MB
  ushort* Wn2r  = (ushort*)(wsp + (67ull << 20) + (512ull << 10));  // 0.5 MB
  ushort* Wfold = (ushort*)(wsp + (68ull << 20));        // 0.5 MB
  float*  T1    = (float*)(wsp + (68ull << 20) + (512ull << 10));   // 1 MB fp32
  int* deg      = (int*)(wsp + (70ull << 20));           // 64 KB
  int* rowstart = deg + kB * kM;
  int* fillptr  = rowstart + kB * kM;
  int* epack    = fillptr + kB * kM;                     // 512 KB
  float* part   = (float*)(wsp + (71ull << 20));         // 1 MB

  // ---- d_out doubles as scratch; all dead before gemm3's out write ----
  char* outc = (char*)d_out;
  ushort* X      = (ushort*)(outc);                   // 16 MB (in-place thru hops)
  ushort* Sxn    = (ushort*)(outc + (16ull << 20));   // 16 MB
  ushort* nSr0n  = (ushort*)(outc + (32ull << 20));   // 16 MB
  float* ENC = out + (size_t)kB * kT * kD;

  // emb + weights -> bf16
  cvt_bf16_k<<<(kV * kD / 4 + 255) / 256, 256, 0, stream>>>(
      (const float4*)emb, (ushort4*)EMBb, kV * kD / 4);
  cvt_bf16_k<<<512, 256, 0, stream>>>((const float4*)Ws, (ushort4*)Wsb, 2 * kD * kD / 4);
  cvt_bf16_k<<<512, 256, 0, stream>>>((const float4*)Wn, (ushort4*)Wnb, 2 * kD * kD / 4);
  cvt_bf16_k<<<768, 256, 0, stream>>>((const float4*)Wt, (ushort4*)Wtb, kD * 1536 / 4);

  // weight folds: Wn2r = Wn2 . Wr1 ; Wfold = Wt2 . Wr2 . Wr1
  smallmm_k<1><<<128, 512, 0, stream>>>(Wn + (size_t)kD * kD, 512, 0, Wr, nullptr, Wn2r);
  smallmm_k<0><<<128, 512, 0, stream>>>(Wt, 1536, 512, Wr + (size_t)kD * kD, T1, nullptr);
  smallmm_k<1><<<128, 512, 0, stream>>>(T1, 512, 0, Wr, nullptr, Wfold);

  // X0 = EMBb[cid]
  gather_rows16_k<<<(kB * kM * 64) / 256, 256, 0, stream>>>(
      (const uint4*)EMBb, cid, (uint4*)X, kB * kM);

  // CSR build (deterministic)
  zero_k<<<(kB * kM + 255) / 256, 256, 0, stream>>>(deg, kB * kM);
  deg_count_k<<<(kB * kT + 255) / 256, 256, 0, stream>>>(headp, tailp, lblp, deg);
  scan_k<<<kB, 1024, 0, stream>>>(deg, rowstart, fillptr);
  fill_k<<<(kB * kT + 255) / 256, 256, 0, stream>>>(headp, tailp, lblp, fillptr, epack);
  sort_k<<<(kB * kM + 255) / 256, 256, 0, stream>>>(rowstart, deg, epack);

  // ---- hop 1: fused X+rel aggregate, then GEMM ----
  agg_xr_k<<<kB * kM, 128, 0, stream>>>(
      (const ushort4*)X, (const ushort4*)EMBb, relid, deg, rowstart, epack,
      (ushort4*)Sxn, (ushort4*)nSr0n);
  gemm_k<0><<<(kB * kM / 128) * 4, 256, 0, stream>>>(
      X, Sxn, nSr0n, Wsb, Wnb, Wnb, X);

  // ---- hop 2 (rel-hop folded via Wn2r) ----
  agg_x_k<<<kB * kM, 128, 0, stream>>>(
      (const ushort4*)X, deg, rowstart, epack, (ushort4*)Sxn);
  gemm_k<0><<<(kB * kM / 128) * 4, 256, 0, stream>>>(
      X, Sxn, nSr0n, Wsb + (size_t)kD * kD, Wnb + (size_t)kD * kD, Wn2r, X);

  // ---- HT = X2 @ [Wt1 | Wt3]^T ----
  gemm_k<4><<<(kB * kM / 128) * 8, 256, 0, stream>>>(
      X, nullptr, nullptr, Wtb, nullptr, nullptr, HT);

  // ---- final: barrier-free reg-fragment GEMM + HT add + partials ----
  gemm3_k<<<(kB * kT / 128) * 4, 256, 0, stream>>>(
      EMBb, Wfold, relid, headp, tailp, HT, out, part);

  // encoded_cause
  reduce_enc_k<<<kB, 512, 0, stream>>>(part, ENC);
}

// Round 10
// 352.061 us; speedup vs baseline: 1.2306x; 1.2306x over previous
//
#include <hip/hip_runtime.h>

namespace {

constexpr int kB = 16;
constexpr int kM = 1024;
constexpr int kT = 4096;
constexpr int kD = 512;
constexpr int kV = 32000;

typedef __attribute__((ext_vector_type(8))) short bfrag8;
typedef __attribute__((ext_vector_type(4))) float f4acc;

__device__ __forceinline__ ushort f2bf(float f) {
  unsigned u = __float_as_uint(f);
  u += 0x7fffu + ((u >> 16) & 1u);
  return (ushort)(u >> 16);
}
__device__ __forceinline__ float bf2f(ushort h) {
  return __uint_as_float(((unsigned)h) << 16);
}

__device__ __forceinline__ void gload_lds16(const void* g, void* l) {
  __builtin_amdgcn_global_load_lds(
      (const __attribute__((address_space(1))) void*)g,
      (__attribute__((address_space(3))) void*)l, 16, 0, 0);
}

// ---------------- fp32 -> bf16 conversion ----------------
__global__ __launch_bounds__(256) void cvt_bf16_k(
    const float4* __restrict__ in, ushort4* __restrict__ out, int n4)
{
  int i = blockIdx.x * 256 + threadIdx.x;
  if (i >= n4) return;
  float4 v = in[i];
  ushort4 o;
  o.x = f2bf(v.x); o.y = f2bf(v.y); o.z = f2bf(v.z); o.w = f2bf(v.w);
  out[i] = o;
}

// ---------------- small 512x512 fp32 matmul: C[e,k] = sum_a P[e,a]*Q[a,k] ----
template<int BF16OUT>
__global__ __launch_bounds__(512) void smallmm_k(
    const float* __restrict__ P, int strideP, int offsP,
    const float* __restrict__ Q,
    float* __restrict__ outf, ushort* __restrict__ outb)
{
  __shared__ float prow[4][512];
  int e0 = blockIdx.x * 4;
  int k = threadIdx.x;
#pragma unroll
  for (int i = 0; i < 4; ++i)
    prow[i][k] = P[(size_t)(e0 + i) * strideP + offsP + k];
  __syncthreads();
  float acc[4] = {0.f, 0.f, 0.f, 0.f};
  for (int a = 0; a < 512; ++a) {
    float qv = Q[a * 512 + k];
#pragma unroll
    for (int i = 0; i < 4; ++i) acc[i] = fmaf(prow[i][a], qv, acc[i]);
  }
#pragma unroll
  for (int i = 0; i < 4; ++i) {
    if constexpr (BF16OUT) outb[(e0 + i) * 512 + k] = f2bf(acc[i]);
    else outf[(e0 + i) * 512 + k] = acc[i];
  }
}

// ---------------- gather bf16 rows (1 KB each) ----------------
__global__ __launch_bounds__(256) void gather_rows16_k(
    const uint4* __restrict__ src, const int* __restrict__ ids,
    uint4* __restrict__ dst, int nrows)
{
  int i = blockIdx.x * 256 + threadIdx.x;
  if (i >= nrows * 64) return;
  int row = i >> 6;
  int c = i & 63;
  dst[i] = src[(size_t)ids[row] * 64 + c];
}

// ---------------- CSR build, O(T) atomic counting-sort (deterministic) ----------
__global__ __launch_bounds__(256) void zero_k(int* __restrict__ p, int n) {
  int i = blockIdx.x * 256 + threadIdx.x;
  if (i < n) p[i] = 0;
}

__global__ __launch_bounds__(256) void deg_count_k(
    const int* __restrict__ headp, const int* __restrict__ tailp,
    const int* __restrict__ lblp, int* __restrict__ deg)
{
  int i = blockIdx.x * 256 + threadIdx.x;
  if (i >= kB * kT) return;
  if (lblp[i] == -1) return;
  int b = i >> 12;
  atomicAdd(&deg[(b << 10) + tailp[i]], 1);
  atomicAdd(&deg[(b << 10) + headp[i]], 1);
}

__global__ __launch_bounds__(1024) void scan_k(
    const int* __restrict__ deg, int* __restrict__ rowstart,
    int* __restrict__ fillptr)
{
  __shared__ int s[kM];
  int b = blockIdx.x;
  int tid = threadIdx.x;
  int d = deg[b * kM + tid];
  s[tid] = d;
  __syncthreads();
  for (int off = 1; off < kM; off <<= 1) {
    int add = (tid >= off) ? s[tid - off] : 0;
    __syncthreads();
    s[tid] += add;
    __syncthreads();
  }
  int rs = b * (2 * kT) + s[tid] - d;
  rowstart[b * kM + tid] = rs;
  fillptr[b * kM + tid] = rs;
}

// pack: (seq = 2t + isHeadEntry) << 10 | src
__global__ __launch_bounds__(256) void fill_k(
    const int* __restrict__ headp, const int* __restrict__ tailp,
    const int* __restrict__ lblp, int* __restrict__ fillptr,
    int* __restrict__ epack)
{
  int i = blockIdx.x * 256 + threadIdx.x;
  if (i >= kB * kT) return;
  if (lblp[i] == -1) return;
  int b = i >> 12;
  int t = i & (kT - 1);
  int hd = headp[i];
  int tl = tailp[i];
  int p0 = atomicAdd(&fillptr[(b << 10) + tl], 1);
  epack[p0] = ((t * 2) << 10) | hd;
  int p1 = atomicAdd(&fillptr[(b << 10) + hd], 1);
  epack[p1] = ((t * 2 + 1) << 10) | tl;
}

__global__ __launch_bounds__(256) void sort_k(
    const int* __restrict__ rowstart, const int* __restrict__ deg,
    int* __restrict__ epack)
{
  int bm = blockIdx.x * 256 + threadIdx.x;
  if (bm >= kB * kM) return;
  int rs = rowstart[bm];
  int dg = deg[bm];
  for (int i = 1; i < dg; ++i) {
    int key = epack[rs + i];
    int j = i - 1;
    while (j >= 0 && epack[rs + j] > key) {
      epack[rs + j + 1] = epack[rs + j];
      --j;
    }
    epack[rs + j + 1] = key;
  }
}

// ---- fused hop-1 aggregate (edge-unrolled x4 for load ILP):
// Sxn = (sum X[src])/cnt ; nSr0n = -(sum EMB[rid])/cnt
__global__ __launch_bounds__(128) void agg_xr_k(
    const ushort4* __restrict__ Xv, const ushort4* __restrict__ EMBv,
    const int* __restrict__ relid,
    const int* __restrict__ deg, const int* __restrict__ rowstart,
    const int* __restrict__ epack,
    ushort4* __restrict__ Sxn, ushort4* __restrict__ nSr0n)
{
  int bm = blockIdx.x;
  int b = bm >> 10;
  int tid = threadIdx.x;
  int dg = deg[bm];
  int rs = rowstart[bm];
  const int* rid = relid + (b << 12);
  size_t xbase = (size_t)b * kM * 128;
  float ax = 0.f, ay = 0.f, az = 0.f, aw = 0.f;
  float rx = 0.f, ry = 0.f, rz = 0.f, rw = 0.f;
  int e = 0;
  for (; e + 4 <= dg; e += 4) {
    int pk[4];
#pragma unroll
    for (int j = 0; j < 4; ++j) pk[j] = epack[rs + e + j];
    ushort4 xv[4], rv[4];
#pragma unroll
    for (int j = 0; j < 4; ++j) {
      xv[j] = Xv[xbase + (size_t)(pk[j] & 1023) * 128 + tid];
      rv[j] = EMBv[(size_t)rid[pk[j] >> 11] * 128 + tid];
    }
#pragma unroll
    for (int j = 0; j < 4; ++j) {
      ax += bf2f(xv[j].x); ay += bf2f(xv[j].y);
      az += bf2f(xv[j].z); aw += bf2f(xv[j].w);
      rx += bf2f(rv[j].x); ry += bf2f(rv[j].y);
      rz += bf2f(rv[j].z); rw += bf2f(rv[j].w);
    }
  }
  for (; e < dg; ++e) {
    int pk = epack[rs + e];
    ushort4 xv = Xv[xbase + (size_t)(pk & 1023) * 128 + tid];
    ushort4 rv = EMBv[(size_t)rid[pk >> 11] * 128 + tid];
    ax += bf2f(xv.x); ay += bf2f(xv.y); az += bf2f(xv.z); aw += bf2f(xv.w);
    rx += bf2f(rv.x); ry += bf2f(rv.y); rz += bf2f(rv.z); rw += bf2f(rv.w);
  }
  float s = 1.0f / (float)(dg > 0 ? dg : 1);
  ushort4 o;
  o.x = f2bf(ax * s); o.y = f2bf(ay * s); o.z = f2bf(az * s); o.w = f2bf(aw * s);
  Sxn[(size_t)bm * 128 + tid] = o;
  o.x = f2bf(-rx * s); o.y = f2bf(-ry * s);
  o.z = f2bf(-rz * s); o.w = f2bf(-rw * s);
  nSr0n[(size_t)bm * 128 + tid] = o;
}

// ---------------- Sxn[bm] = (sum_edges X[src]) / max(cnt,1), unrolled x4 ------
__global__ __launch_bounds__(128) void agg_x_k(
    const ushort4* __restrict__ Xv,
    const int* __restrict__ deg, const int* __restrict__ rowstart,
    const int* __restrict__ epack, ushort4* __restrict__ outv)
{
  int bm = blockIdx.x;
  int b = bm >> 10;
  int tid = threadIdx.x;
  int dg = deg[bm];
  int rs = rowstart[bm];
  size_t xbase = (size_t)b * kM * 128;
  float ax = 0.f, ay = 0.f, az = 0.f, aw = 0.f;
  int e = 0;
  for (; e + 4 <= dg; e += 4) {
    int pk[4];
#pragma unroll
    for (int j = 0; j < 4; ++j) pk[j] = epack[rs + e + j];
    ushort4 xv[4];
#pragma unroll
    for (int j = 0; j < 4; ++j)
      xv[j] = Xv[xbase + (size_t)(pk[j] & 1023) * 128 + tid];
#pragma unroll
    for (int j = 0; j < 4; ++j) {
      ax += bf2f(xv[j].x); ay += bf2f(xv[j].y);
      az += bf2f(xv[j].z); aw += bf2f(xv[j].w);
    }
  }
  for (; e < dg; ++e) {
    int src = epack[rs + e] & 1023;
    ushort4 xv = Xv[xbase + (size_t)src * 128 + tid];
    ax += bf2f(xv.x); ay += bf2f(xv.y); az += bf2f(xv.z); aw += bf2f(xv.w);
  }
  float s = 1.0f / (float)(dg > 0 ? dg : 1);
  ushort4 o;
  o.x = f2bf(ax * s); o.y = f2bf(ay * s); o.z = f2bf(az * s); o.w = f2bf(aw * s);
  outv[(size_t)bm * 128 + tid] = o;
}

// ---------------- bf16 MFMA GEMM (128x128 tile, 2-barrier LDS loop) ----------
// MODE 0: C = relu([X|Sxn|nSr0n] @ [W1|W2|W3]^T), K=1536, in-place X. SWZ.
// MODE 4: C = X2 @ [Wt1|Wt3]^T (N=1024, bf16 out stride 1024). SWZ.
template<int MODE>
__global__ __launch_bounds__(256) void gemm_k(
    const ushort* __restrict__ A0, const ushort* __restrict__ A1,
    const ushort* __restrict__ A2,
    const ushort* __restrict__ W1, const ushort* __restrict__ W2,
    const ushort* __restrict__ W3,
    ushort* __restrict__ outbf)
{
  constexpr int NSEG = (MODE == 0) ? 3 : 1;
  constexpr int NC = (MODE == 4) ? 8 : 4;
  constexpr int OSTR = (MODE == 4) ? 1024 : 512;

  __shared__ __align__(16) char lds[32768];
  char* ldsA = lds;
  char* ldsB = lds + 16384;
  const int tid = threadIdx.x;
  const int w = tid >> 6;
  const int l = tid & 63;
  const int wr = w >> 1;
  const int wc = w & 1;
  const int bid = blockIdx.x;
  const int xcd = bid & 7;
  const int idx = bid >> 3;
  const int panel = xcd * (((int)gridDim.x >> 3) / NC) + idx / NC;
  const int col = idx % NC;
  const int rowBase = panel * 128;
  const int colBase = col * 128;

  f4acc acc[4][4];
#pragma unroll
  for (int i = 0; i < 4; ++i)
#pragma unroll
    for (int j = 0; j < 4; ++j) acc[i][j] = (f4acc)(0.f);

  int lrow[4], gc[4];
#pragma unroll
  for (int i = 0; i < 4; ++i) {
    int P = (i * 4 + w) * 64 + l;
    lrow[i] = P >> 3;
    gc[i] = (P & 7) ^ (lrow[i] & 7);
  }

  for (int seg = 0; seg < NSEG; ++seg) {
    const char* aP[4];
    const char* bP[4];
#pragma unroll
    for (int i = 0; i < 4; ++i) {
      int grow = rowBase + lrow[i];
      const ushort* ab;
      if constexpr (MODE == 0) {
        ab = (seg == 0 ? A0 : (seg == 1 ? A1 : A2)) + (size_t)grow * kD;
      } else {
        ab = A0 + (size_t)grow * kD;
      }
      aP[i] = (const char*)ab + gc[i] * 16;
      int e = colBase + lrow[i];
      const ushort* wb;
      if constexpr (MODE == 0) {
        wb = (seg == 0 ? W1 : (seg == 1 ? W2 : W3)) + (size_t)e * kD;
      } else {
        wb = W1 + (size_t)(e & 511) * 1536 + (e >> 9) * 1024;
      }
      bP[i] = (const char*)wb + gc[i] * 16;
    }
    for (int kcl = 0; kcl < 8; ++kcl) {
      __syncthreads();
#pragma unroll
      for (int i = 0; i < 4; ++i) {
        gload_lds16(aP[i] + kcl * 128, ldsA + (i * 4 + w) * 1024);
        gload_lds16(bP[i] + kcl * 128, ldsB + (i * 4 + w) * 1024);
      }
      __syncthreads();
#pragma unroll
      for (int ksub = 0; ksub < 2; ++ksub) {
        bfrag8 ef[4], wf[4];
#pragma unroll
        for (int mi = 0; mi < 4; ++mi) {
          int r = wr * 64 + mi * 16 + (l & 15);
          int g = (ksub * 4 + (l >> 4)) ^ (r & 7);
          ef[mi] = *(const bfrag8*)(ldsA + r * 128 + g * 16);
        }
#pragma unroll
        for (int ni = 0; ni < 4; ++ni) {
          int e = wc * 64 + ni * 16 + (l & 15);
          int g = (ksub * 4 + (l >> 4)) ^ (e & 7);
          wf[ni] = *(const bfrag8*)(ldsB + e * 128 + g * 16);
        }
#pragma unroll
        for (int mi = 0; mi < 4; ++mi)
#pragma unroll
          for (int ni = 0; ni < 4; ++ni)
            acc[mi][ni] = __builtin_amdgcn_mfma_f32_16x16x32_bf16(
                wf[ni], ef[mi], acc[mi][ni], 0, 0, 0);
      }
    }
  }

  // epilogue (swapped layout): row = ..+(l&15); cols 4-consecutive
#pragma unroll
  for (int mi = 0; mi < 4; ++mi) {
    int rr = rowBase + wr * 64 + mi * 16 + (l & 15);
#pragma unroll
    for (int ni = 0; ni < 4; ++ni) {
      int cc0 = colBase + wc * 64 + ni * 16 + (l >> 4) * 4;
      float v0 = acc[mi][ni][0], v1 = acc[mi][ni][1];
      float v2 = acc[mi][ni][2], v3 = acc[mi][ni][3];
      if constexpr (MODE == 0) {
        v0 = fmaxf(v0, 0.f); v1 = fmaxf(v1, 0.f);
        v2 = fmaxf(v2, 0.f); v3 = fmaxf(v3, 0.f);
      }
      ushort4 o;
      o.x = f2bf(v0); o.y = f2bf(v1); o.z = f2bf(v2); o.w = f2bf(v3);
      *(ushort4*)(outbf + (size_t)rr * OSTR + cc0) = o;
    }
  }
}

// ---------------- final GEMM (r6 K-loop, unswizzled; r7 vectorized epilogue) --
// out = EMBb[relid] @ Wfold^T + HT[head].H + HT[tail].T (fp32) + col partials.
__global__ __launch_bounds__(256) void gemm3_k(
    const ushort* __restrict__ EMBb, const ushort* __restrict__ Wf,
    const int* __restrict__ relid, const int* __restrict__ headp,
    const int* __restrict__ tailp, const ushort* __restrict__ HT,
    float* __restrict__ outf, float* __restrict__ part)
{
  __shared__ __align__(16) char lds[32768];
  char* ldsA = lds;
  char* ldsB = lds + 16384;
  const int tid = threadIdx.x;
  const int w = tid >> 6;
  const int l = tid & 63;
  const int wr = w >> 1;
  const int wc = w & 1;
  const int bid = blockIdx.x;
  const int rowBase = (bid >> 2) * 128;   // unswizzled (measured best)
  const int colBase = (bid & 3) * 128;

  f4acc acc[4][4];
#pragma unroll
  for (int i = 0; i < 4; ++i)
#pragma unroll
    for (int j = 0; j < 4; ++j) acc[i][j] = (f4acc)(0.f);

  int lrow[4], gc[4];
  const char* aP[4];
  const char* bP[4];
#pragma unroll
  for (int i = 0; i < 4; ++i) {
    int P = (i * 4 + w) * 64 + l;
    lrow[i] = P >> 3;
    gc[i] = (P & 7) ^ (lrow[i] & 7);
    aP[i] = (const char*)(EMBb + (size_t)relid[rowBase + lrow[i]] * kD) + gc[i] * 16;
    bP[i] = (const char*)(Wf + (size_t)(colBase + lrow[i]) * kD) + gc[i] * 16;
  }

  for (int kcl = 0; kcl < 8; ++kcl) {
    __syncthreads();
#pragma unroll
    for (int i = 0; i < 4; ++i) {
      gload_lds16(aP[i] + kcl * 128, ldsA + (i * 4 + w) * 1024);
      gload_lds16(bP[i] + kcl * 128, ldsB + (i * 4 + w) * 1024);
    }
    __syncthreads();
#pragma unroll
    for (int ksub = 0; ksub < 2; ++ksub) {
      bfrag8 ef[4], wf[4];
#pragma unroll
      for (int mi = 0; mi < 4; ++mi) {
        int r = wr * 64 + mi * 16 + (l & 15);
        int g = (ksub * 4 + (l >> 4)) ^ (r & 7);
        ef[mi] = *(const bfrag8*)(ldsA + r * 128 + g * 16);
      }
#pragma unroll
      for (int ni = 0; ni < 4; ++ni) {
        int e = wc * 64 + ni * 16 + (l & 15);
        int g = (ksub * 4 + (l >> 4)) ^ (e & 7);
        wf[ni] = *(const bfrag8*)(ldsB + e * 128 + g * 16);
      }
#pragma unroll
      for (int mi = 0; mi < 4; ++mi)
#pragma unroll
        for (int ni = 0; ni < 4; ++ni)
          acc[mi][ni] = __builtin_amdgcn_mfma_f32_16x16x32_bf16(
              wf[ni], ef[mi], acc[mi][ni], 0, 0, 0);
    }
  }

  // vectorized epilogue: rr from (l&15); 4 consecutive cols per frag
  __shared__ float colsum[2][128];
  colsum[tid >> 7][tid & 127] = 0.f;
  __syncthreads();
  const int sl = l >> 4;
  float cs[4][4];
#pragma unroll
  for (int ni = 0; ni < 4; ++ni)
#pragma unroll
    for (int q = 0; q < 4; ++q) cs[ni][q] = 0.f;
#pragma unroll
  for (int mi = 0; mi < 4; ++mi) {
    int rr = rowBase + wr * 64 + mi * 16 + (l & 15);
    int bb = rr >> 12;
    int hid = headp[rr];
    int tl = tailp[rr];
    const ushort* Hrow = HT + ((size_t)(bb << 10) + hid) * 1024;
    const ushort* Trow = HT + ((size_t)(bb << 10) + tl) * 1024 + 512;
#pragma unroll
    for (int ni = 0; ni < 4; ++ni) {
      int cc0 = colBase + wc * 64 + ni * 16 + sl * 4;
      ushort4 hv = *(const ushort4*)(Hrow + cc0);
      ushort4 tv = *(const ushort4*)(Trow + cc0);
      float4 ov;
      ov.x = acc[mi][ni][0] + bf2f(hv.x) + bf2f(tv.x);
      ov.y = acc[mi][ni][1] + bf2f(hv.y) + bf2f(tv.y);
      ov.z = acc[mi][ni][2] + bf2f(hv.z) + bf2f(tv.z);
      ov.w = acc[mi][ni][3] + bf2f(hv.w) + bf2f(tv.w);
      cs[ni][0] += ov.x; cs[ni][1] += ov.y;
      cs[ni][2] += ov.z; cs[ni][3] += ov.w;
      *(float4*)(outf + (size_t)rr * 512 + cc0) = ov;
    }
  }
#pragma unroll
  for (int ni = 0; ni < 4; ++ni) {
#pragma unroll
    for (int q = 0; q < 4; ++q) {
      float s = cs[ni][q];
      s += __shfl_xor(s, 1);
      s += __shfl_xor(s, 2);
      s += __shfl_xor(s, 4);
      s += __shfl_xor(s, 8);
      if ((l & 15) == 0)
        colsum[wr][wc * 64 + ni * 16 + sl * 4 + q] = s;
    }
  }
  __syncthreads();
  if (tid < 128) {
    int bb = rowBase >> 12;
    int rt = (rowBase >> 7) & 31;
    part[(size_t)(bb * 32 + rt) * 512 + colBase + tid] =
        colsum[0][tid] + colsum[1][tid];
  }
}

// ---------------- encoded_cause: sum 32 row-tile partials per batch ----------
__global__ __launch_bounds__(512) void reduce_enc_k(
    const float* __restrict__ part, float* __restrict__ enc)
{
  int b = blockIdx.x;
  int c = threadIdx.x;
  float s = 0.f;
  for (int rt = 0; rt < 32; ++rt) s += part[(size_t)(b * 32 + rt) * 512 + c];
  enc[b * 512 + c] = s;
}

}  // namespace

extern "C" void kernel_launch(void* const* d_in, const int* in_sizes, int n_in,
                              void* d_out, int out_size, void* d_ws, size_t ws_size,
                              hipStream_t stream) {
  const float* emb = (const float*)d_in[0];
  const float* Ws = (const float*)d_in[1];
  const float* Wn = (const float*)d_in[2];
  const float* Wr = (const float*)d_in[3];
  const float* Wt = (const float*)d_in[4];
  const int* cid = (const int*)d_in[5];
  const int* relid = (const int*)d_in[6];
  const int* headp = (const int*)d_in[7];
  const int* tailp = (const int*)d_in[8];
  const int* lblp = (const int*)d_in[9];
  float* out = (float*)d_out;

  // ---- ws layout (~72 MB) ----
  char* wsp = (char*)d_ws;
  ushort* EMBb  = (ushort*)(wsp);                        // 31.25 MB @0
  ushort* HT    = (ushort*)(wsp + (32ull << 20));        // 32 MB @32
  ushort* Wsb   = (ushort*)(wsp + (64ull << 20));        // 1 MB (2 hops)
  ushort* Wnb   = (ushort*)(wsp + (65ull << 20));        // 1 MB (2 hops)
  ushort* Wtb   = (ushort*)(wsp + (66ull << 20));        // 1.5 MB
  ushort* Wn2r  = (ushort*)(wsp + (67ull << 20) + (512ull << 10));  // 0.5 MB
  ushort* Wfold = (ushort*)(wsp + (68ull << 20));        // 0.5 MB
  float*  T1    = (float*)(wsp + (68ull << 20) + (512ull << 10));   // 1 MB fp32
  int* deg      = (int*)(wsp + (70ull << 20));           // 64 KB
  int* rowstart = deg + kB * kM;
  int* fillptr  = rowstart + kB * kM;
  int* epack    = fillptr + kB * kM;                     // 512 KB
  float* part   = (float*)(wsp + (71ull << 20));         // 1 MB

  // ---- d_out doubles as scratch; all dead before gemm3's out write ----
  char* outc = (char*)d_out;
  ushort* X      = (ushort*)(outc);                   // 16 MB (in-place thru hops)
  ushort* Sxn    = (ushort*)(outc + (16ull << 20));   // 16 MB
  ushort* nSr0n  = (ushort*)(outc + (32ull << 20));   // 16 MB
  float* ENC = out + (size_t)kB * kT * kD;

  // emb + weights -> bf16
  cvt_bf16_k<<<(kV * kD / 4 + 255) / 256, 256, 0, stream>>>(
      (const float4*)emb, (ushort4*)EMBb, kV * kD / 4);
  cvt_bf16_k<<<512, 256, 0, stream>>>((const float4*)Ws, (ushort4*)Wsb, 2 * kD * kD / 4);
  cvt_bf16_k<<<512, 256, 0, stream>>>((const float4*)Wn, (ushort4*)Wnb, 2 * kD * kD / 4);
  cvt_bf16_k<<<768, 256, 0, stream>>>((const float4*)Wt, (ushort4*)Wtb, kD * 1536 / 4);

  // weight folds: Wn2r = Wn2 . Wr1 ; Wfold = Wt2 . Wr2 . Wr1
  smallmm_k<1><<<128, 512, 0, stream>>>(Wn + (size_t)kD * kD, 512, 0, Wr, nullptr, Wn2r);
  smallmm_k<0><<<128, 512, 0, stream>>>(Wt, 1536, 512, Wr + (size_t)kD * kD, T1, nullptr);
  smallmm_k<1><<<128, 512, 0, stream>>>(T1, 512, 0, Wr, nullptr, Wfold);

  // X0 = EMBb[cid]
  gather_rows16_k<<<(kB * kM * 64) / 256, 256, 0, stream>>>(
      (const uint4*)EMBb, cid, (uint4*)X, kB * kM);

  // CSR build (deterministic)
  zero_k<<<(kB * kM + 255) / 256, 256, 0, stream>>>(deg, kB * kM);
  deg_count_k<<<(kB * kT + 255) / 256, 256, 0, stream>>>(headp, tailp, lblp, deg);
  scan_k<<<kB, 1024, 0, stream>>>(deg, rowstart, fillptr);
  fill_k<<<(kB * kT + 255) / 256, 256, 0, stream>>>(headp, tailp, lblp, fillptr, epack);
  sort_k<<<(kB * kM + 255) / 256, 256, 0, stream>>>(rowstart, deg, epack);

  // ---- hop 1: fused X+rel aggregate, then GEMM ----
  agg_xr_k<<<kB * kM, 128, 0, stream>>>(
      (const ushort4*)X, (const ushort4*)EMBb, relid, deg, rowstart, epack,
      (ushort4*)Sxn, (ushort4*)nSr0n);
  gemm_k<0><<<(kB * kM / 128) * 4, 256, 0, stream>>>(
      X, Sxn, nSr0n, Wsb, Wnb, Wnb, X);

  // ---- hop 2 (rel-hop folded via Wn2r) ----
  agg_x_k<<<kB * kM, 128, 0, stream>>>(
      (const ushort4*)X, deg, rowstart, epack, (ushort4*)Sxn);
  gemm_k<0><<<(kB * kM / 128) * 4, 256, 0, stream>>>(
      X, Sxn, nSr0n, Wsb + (size_t)kD * kD, Wnb + (size_t)kD * kD, Wn2r, X);

  // ---- HT = X2 @ [Wt1 | Wt3]^T ----
  gemm_k<4><<<(kB * kM / 128) * 8, 256, 0, stream>>>(
      X, nullptr, nullptr, Wtb, nullptr, nullptr, HT);

  // ---- final: LDS GEMM + HT add + partials ----
  gemm3_k<<<(kB * kT / 128) * 4, 256, 0, stream>>>(
      EMBb, Wfold, relid, headp, tailp, HT, out, part);

  // encoded_cause
  reduce_enc_k<<<kB, 512, 0, stream>>>(part, ENC);
}